// Round 4
// baseline (112.992 us; speedup 1.0000x reference)
//
#include <hip/hip_runtime.h>
#include <math.h>

#define B_    2
#define C_    64
#define N_    20000
#define K_    16
#define COUT_ 64
#define TNC   64
#define NBC   ((N_ + TNC - 1) / TNC)   // 313
#define TN    16
#define NB    (N_ / TN)                // 1250 (exact)

typedef unsigned int   u32;
typedef unsigned short u16;
typedef __attribute__((ext_vector_type(8))) short bf16x8;   // 8 bf16 = 4 VGPR
typedef __attribute__((ext_vector_type(4))) float f32x4;

static __device__ __forceinline__ u16 f2bf(float f) {
    union { float f; u32 u; } v; v.f = f;
    u32 r = (v.u + 0x7FFFu + ((v.u >> 16) & 1u)) >> 16;  // RNE
    return (u16)r;
}
static __device__ __forceinline__ float uasf(u32 u) {
    union { u32 u; float f; } v; v.u = u; return v.f;
}
// packed bf16 pair subtract: (b - a) elementwise on two bf16 in a u32
static __device__ __forceinline__ u32 bfsub2(u32 bv, u32 av) {
    float bl = uasf(bv << 16), bh = uasf(bv & 0xFFFF0000u);
    float al = uasf(av << 16), ah = uasf(av & 0xFFFF0000u);
    return (u32)f2bf(bl - al) | ((u32)f2bf(bh - ah) << 16);
}

// XOR swizzle for row-major [*][128]bf16 (256 B rows) LDS tiles (G4 recipe)
#define SWZ(row, off) ((off) ^ (((row) & 7) << 4))

// ---------------------------------------------------------------------------
// precast: blocks 0..B*NBC-1: transpose+cast x [b][c][n] f32 -> xb [b][n][64]
// bf16 (128 B rows; per-batch table = 2.56 MB -> fits one XCD L2).
// Last block: pack W (f32 [64][128]) into MFMA B-fragment layout, bf16:
// wfrag[(ot*4+ks)*64 + lane][j] = W[ot*16 + (lane&15)][ks*32 + (lane>>4)*8 + j]
// ---------------------------------------------------------------------------
__global__ __launch_bounds__(256)
void precast(const float* __restrict__ x, const float* __restrict__ W,
             u16* __restrict__ xb, u16* __restrict__ wfrag) {
    const int bi = blockIdx.x;
    const int t  = threadIdx.x;

    if (bi == B_ * NBC) {               // ---- W-fragment packer (1 block) ----
        const int l  = t & 63;
        const int ot = t >> 6;
        const int ro = (ot * 16 + (l & 15)) * 128 + ((l >> 4) << 3);
        #pragma unroll
        for (int ks = 0; ks < 4; ++ks) {
            u32 p[4];
            #pragma unroll
            for (int jj = 0; jj < 4; ++jj) {
                float v0 = W[ro + ks * 32 + 2 * jj];
                float v1 = W[ro + ks * 32 + 2 * jj + 1];
                p[jj] = (u32)f2bf(v0) | ((u32)f2bf(v1) << 16);
            }
            *(uint4*)&wfrag[(size_t)((ot * 4 + ks) * 64 + l) * 8] =
                make_uint4(p[0], p[1], p[2], p[3]);
        }
        return;
    }

    __shared__ float tile[64][68];      // [c][n_local], padded
    const int b  = bi / NBC;
    const int n0 = (bi % NBC) * TNC;
    const float* xbase = x + (size_t)b * C_ * N_;
    #pragma unroll
    for (int r = 0; r < 4; ++r) {
        int flat = r * 256 + t;
        int c = flat >> 4, ng = (flat & 15) * 4;
        int n = n0 + ng;
        float4 v;
        if (n + 3 < N_) {
            v = *(const float4*)&xbase[c * N_ + n];
        } else {
            v.x = (n     < N_) ? xbase[c * N_ + n    ] : 0.0f;
            v.y = (n + 1 < N_) ? xbase[c * N_ + n + 1] : 0.0f;
            v.z = (n + 2 < N_) ? xbase[c * N_ + n + 2] : 0.0f;
            v.w = (n + 3 < N_) ? xbase[c * N_ + n + 3] : 0.0f;
        }
        *(float4*)&tile[c][ng] = v;
    }
    __syncthreads();

    const int n = t >> 2, q = t & 3;    // node row, 16-channel quarter
    if (n0 + n < N_) {
        u32 p[8];
        #pragma unroll
        for (int jj = 0; jj < 8; ++jj) {
            float v0 = tile[q * 16 + 2 * jj][n];
            float v1 = tile[q * 16 + 2 * jj + 1][n];
            p[jj] = (u32)f2bf(v0) | ((u32)f2bf(v1) << 16);
        }
        u16* dst = xb + ((size_t)(b * N_ + n0 + n)) * 64 + q * 16;
        *(uint4*)dst       = make_uint4(p[0], p[1], p[2], p[3]);
        *(uint4*)(dst + 8) = make_uint4(p[4], p[5], p[6], p[7]);
    }
}

// ---------------------------------------------------------------------------
// fused: per block 16 nodes = 256 edges.
// A: edge prep (1/thread): i0(neighbor), i1(center), s=2*sigmoid(-dis) -> LDS
// B: gather x rows from the L2-resident bf16 table, build
//    feat[e][0:64]=x_i, feat[e][64:128]=x_j-x_i in XOR-swizzled LDS
// C: MFMA 16x16x32_bf16: D[e-tile][o-tile] = feat x W^T; epilogue
//    relu(D+b)*s, k-max inside the D fragment (col=lane&15,
//    row=(lane>>4)*4+reg), shfl_xor(16/32) across row-groups.
// ---------------------------------------------------------------------------
__global__ __launch_bounds__(256)
void fused(const int* __restrict__ ei, const float* __restrict__ pos,
           const u16* __restrict__ xb, const u16* __restrict__ wfrag,
           const float* __restrict__ bias, float* __restrict__ out) {
    __shared__ u16   feat[256 * 128];   // 64 KB, swizzled 256 B rows
    __shared__ uint2 esl[256];          // (i0 | i1<<16, s)
    __shared__ float otile[16][66];     // [n_local][o], padded

    const int bi   = blockIdx.x;
    const int b    = bi / NB;
    const int n0   = (bi % NB) * TN;
    const int t    = threadIdx.x;
    const int lane = t & 63;
    const int w    = t >> 6;
    const int g    = lane >> 4;         // 16-lane group 0..3

    // ---- Phase A: edge prep ----
    {
        const int idx = n0 * K_ + t;                     // coalesced
        int i0 = ei[(size_t)b * N_ * K_ + idx];          // neighbor (x_j)
        int i1 = ei[((size_t)B_ + b) * N_ * K_ + idx];   // center   (x_i)
        const float* pb = pos + (size_t)b * 3 * N_;
        float dx = pb[i0]          - pb[i1];
        float dy = pb[N_ + i0]     - pb[N_ + i1];
        float dz = pb[2 * N_ + i0] - pb[2 * N_ + i1];
        float dis = sqrtf(dx * dx + dy * dy + dz * dz);
        float s = 2.0f / (1.0f + __expf(dis));           // 2*sigmoid(-dis)
        esl[t] = make_uint2((u32)i0 | ((u32)i1 << 16), __float_as_uint(s));
    }
    __syncthreads();

    // ---- Phase B: gather + feat build (8 passes, 32 edges/pass) ----
    {
        const uint4* xrow = (const uint4*)(xb + (size_t)b * N_ * 64);
        const int cq = t & 7;                            // 16 B chunk
        char* fb = (char*)feat;
        #pragma unroll
        for (int p = 0; p < 8; ++p) {
            int e = p * 32 + (t >> 3);
            uint2 ee = esl[e];
            int i0 = (int)(ee.x & 0xFFFFu);
            int i1 = (int)(ee.x >> 16);
            uint4 a  = xrow[((size_t)i1 << 3) + cq];     // x_i chunk (bf16)
            uint4 bv = xrow[((size_t)i0 << 3) + cq];     // x_j chunk
            *(uint4*)(fb + SWZ(e, e * 256 + cq * 16)) = a;
            uint4 d;
            d.x = bfsub2(bv.x, a.x);
            d.y = bfsub2(bv.y, a.y);
            d.z = bfsub2(bv.z, a.z);
            d.w = bfsub2(bv.w, a.w);
            *(uint4*)(fb + SWZ(e, e * 256 + 128 + cq * 16)) = d;
        }
    }

    // ---- W fragments: 16 x 16 B coalesced loads (L1/L2-hot) ----
    bf16x8 wf[16];
    #pragma unroll
    for (int f = 0; f < 16; ++f)
        wf[f] = *(const bf16x8*)&wfrag[(size_t)(f * 64 + lane) * 8];

    const int col = lane & 15;
    const float bo0 = bias[col], bo1 = bias[16 + col],
                bo2 = bias[32 + col], bo3 = bias[48 + col];
    __syncthreads();

    // ---- Phase C: MFMA + epilogue, wave w owns nodes {w, w+4, w+8, w+12} ----
    const char* fb = (const char*)feat;
    #pragma unroll
    for (int it = 0; it < 4; ++it) {
        const int et  = it * 4 + w;
        const int row = et * 16 + col;
        const int rb  = row * 256 + g * 16;
        bf16x8 a0 = *(const bf16x8*)(fb + SWZ(row, rb));
        bf16x8 a1 = *(const bf16x8*)(fb + SWZ(row, rb + 64));
        bf16x8 a2 = *(const bf16x8*)(fb + SWZ(row, rb + 128));
        bf16x8 a3 = *(const bf16x8*)(fb + SWZ(row, rb + 192));
        f32x4 ac0 = {0,0,0,0}, ac1 = ac0, ac2 = ac0, ac3 = ac0;
        ac0 = __builtin_amdgcn_mfma_f32_16x16x32_bf16(a0, wf[0],  ac0, 0,0,0);
        ac0 = __builtin_amdgcn_mfma_f32_16x16x32_bf16(a1, wf[1],  ac0, 0,0,0);
        ac0 = __builtin_amdgcn_mfma_f32_16x16x32_bf16(a2, wf[2],  ac0, 0,0,0);
        ac0 = __builtin_amdgcn_mfma_f32_16x16x32_bf16(a3, wf[3],  ac0, 0,0,0);
        ac1 = __builtin_amdgcn_mfma_f32_16x16x32_bf16(a0, wf[4],  ac1, 0,0,0);
        ac1 = __builtin_amdgcn_mfma_f32_16x16x32_bf16(a1, wf[5],  ac1, 0,0,0);
        ac1 = __builtin_amdgcn_mfma_f32_16x16x32_bf16(a2, wf[6],  ac1, 0,0,0);
        ac1 = __builtin_amdgcn_mfma_f32_16x16x32_bf16(a3, wf[7],  ac1, 0,0,0);
        ac2 = __builtin_amdgcn_mfma_f32_16x16x32_bf16(a0, wf[8],  ac2, 0,0,0);
        ac2 = __builtin_amdgcn_mfma_f32_16x16x32_bf16(a1, wf[9],  ac2, 0,0,0);
        ac2 = __builtin_amdgcn_mfma_f32_16x16x32_bf16(a2, wf[10], ac2, 0,0,0);
        ac2 = __builtin_amdgcn_mfma_f32_16x16x32_bf16(a3, wf[11], ac2, 0,0,0);
        ac3 = __builtin_amdgcn_mfma_f32_16x16x32_bf16(a0, wf[12], ac3, 0,0,0);
        ac3 = __builtin_amdgcn_mfma_f32_16x16x32_bf16(a1, wf[13], ac3, 0,0,0);
        ac3 = __builtin_amdgcn_mfma_f32_16x16x32_bf16(a2, wf[14], ac3, 0,0,0);
        ac3 = __builtin_amdgcn_mfma_f32_16x16x32_bf16(a3, wf[15], ac3, 0,0,0);

        float m0 = 0.f, m1 = 0.f, m2 = 0.f, m3 = 0.f;   // relu*s >= 0
#define EPI(REG) { \
        float sv = uasf(esl[et * 16 + g * 4 + REG].y); \
        m0 = fmaxf(m0, fmaxf(ac0[REG] + bo0, 0.f) * sv); \
        m1 = fmaxf(m1, fmaxf(ac1[REG] + bo1, 0.f) * sv); \
        m2 = fmaxf(m2, fmaxf(ac2[REG] + bo2, 0.f) * sv); \
        m3 = fmaxf(m3, fmaxf(ac3[REG] + bo3, 0.f) * sv); }
        EPI(0) EPI(1) EPI(2) EPI(3)
#undef EPI
        m0 = fmaxf(m0, __shfl_xor(m0, 16)); m0 = fmaxf(m0, __shfl_xor(m0, 32));
        m1 = fmaxf(m1, __shfl_xor(m1, 16)); m1 = fmaxf(m1, __shfl_xor(m1, 32));
        m2 = fmaxf(m2, __shfl_xor(m2, 16)); m2 = fmaxf(m2, __shfl_xor(m2, 32));
        m3 = fmaxf(m3, __shfl_xor(m3, 16)); m3 = fmaxf(m3, __shfl_xor(m3, 32));
        if (lane < 16) {
            otile[et][col]      = m0;
            otile[et][16 + col] = m1;
            otile[et][32 + col] = m2;
            otile[et][48 + col] = m3;
        }
    }
    __syncthreads();

    // ---- coalesced writeback: 64 o x 16 n, nontemporal ----
    #pragma unroll
    for (int r = 0; r < 4; ++r) {
        int flat = r * 256 + t;
        int o = flat >> 4, n2 = flat & 15;
        __builtin_nontemporal_store(otile[n2][o],
            &out[((size_t)b * COUT_ + o) * N_ + n0 + n2]);
    }
}

// ---------------------------------------------------------------------------
extern "C" void kernel_launch(void* const* d_in, const int* in_sizes, int n_in,
                              void* d_out, int out_size, void* d_ws, size_t ws_size,
                              hipStream_t stream) {
    const float* x    = (const float*)d_in[0];   // [B, C, N, 1]
    const int*   ei   = (const int*)  d_in[1];   // [2, B, N, K]
    const float* pos  = (const float*)d_in[2];   // [B, 3, N, 1]
    const float* W    = (const float*)d_in[3];   // [COUT, 2C]
    const float* bias = (const float*)d_in[4];   // [COUT]
    float*       out  = (float*)d_out;           // [B, COUT, N, 1]

    u16* xb    = (u16*)d_ws;                     // B*N*64 bf16 = 5.12 MB
    u16* wfrag = xb + (size_t)B_ * N_ * 64;      // 16 KB (B-frag layout)

    hipLaunchKernelGGL(precast, dim3(B_ * NBC + 1), dim3(256), 0, stream,
                       x, W, xb, wfrag);
    hipLaunchKernelGGL(fused, dim3(B_ * NB), dim3(256), 0, stream,
                       ei, pos, xb, wfrag, bias, out);
}

// Round 5
// 110.729 us; speedup vs baseline: 1.0204x; 1.0204x over previous
//
#include <hip/hip_runtime.h>
#include <math.h>

#define B_    2
#define C_    64
#define N_    20000
#define K_    16
#define COUT_ 64
#define TNC   64
#define NBC   ((N_ + TNC - 1) / TNC)   // 313
#define TN    16
#define NB    (N_ / TN)                // 1250 (exact)

typedef unsigned int   u32;
typedef unsigned short u16;
typedef __attribute__((ext_vector_type(8))) short bf16x8;   // 8 bf16 = 4 VGPR
typedef __attribute__((ext_vector_type(4))) float f32x4;

static __device__ __forceinline__ u16 f2bf(float f) {
    union { float f; u32 u; } v; v.f = f;
    u32 r = (v.u + 0x7FFFu + ((v.u >> 16) & 1u)) >> 16;  // RNE
    return (u16)r;
}
static __device__ __forceinline__ float uasf(u32 u) {
    union { u32 u; float f; } v; v.u = u; return v.f;
}
static __device__ __forceinline__ bf16x8 asbf(uint4 v) {
    union { uint4 u; bf16x8 b; } c; c.u = v; return c.b;
}

// ---------------------------------------------------------------------------
// precast: blocks 0..B*NBC-1: transpose+cast x [b][c][n] f32 -> xb [b][n][64]
// bf16 (128 B rows; per-batch table = 2.56 MB -> fits one XCD L2).
// Last block packs MFMA B-fragments (bf16):
//   f = ot*4 + {0,1}: (W1-W2) cols {0..31, 32..63}
//   f = ot*4 + {2,3}:  W2     cols {0..31, 32..63}
// so feat x W^T = x_i (W1-W2)^T + x_j W2^T needs NO per-edge subtraction.
// ---------------------------------------------------------------------------
__global__ __launch_bounds__(256)
void precast(const float* __restrict__ x, const float* __restrict__ W,
             u16* __restrict__ xb, u16* __restrict__ wfrag) {
    const int bi = blockIdx.x;
    const int t  = threadIdx.x;

    if (bi == B_ * NBC) {               // ---- W-fragment packer (1 block) ----
        const int l  = t & 63;
        const int ot = t >> 6;
        const int o  = ot * 16 + (l & 15);
        const int cb = (l >> 4) << 3;   // 8-ch chunk within a 32-col slice
        #pragma unroll
        for (int h = 0; h < 2; ++h) {   // col half: channels h*32 + cb .. +8
            u32 p1[4], p2[4];
            #pragma unroll
            for (int jj = 0; jj < 4; ++jj) {
                int c0 = h * 32 + cb + 2 * jj, c1 = c0 + 1;
                float w1a = W[o * 128 + c0],      w1b = W[o * 128 + c1];
                float w2a = W[o * 128 + 64 + c0], w2b = W[o * 128 + 64 + c1];
                p1[jj] = (u32)f2bf(w1a - w2a) | ((u32)f2bf(w1b - w2b) << 16);
                p2[jj] = (u32)f2bf(w2a)       | ((u32)f2bf(w2b)       << 16);
            }
            *(uint4*)&wfrag[(size_t)((ot * 4 + h)     * 64 + l) * 8] =
                make_uint4(p1[0], p1[1], p1[2], p1[3]);
            *(uint4*)&wfrag[(size_t)((ot * 4 + 2 + h) * 64 + l) * 8] =
                make_uint4(p2[0], p2[1], p2[2], p2[3]);
        }
        return;
    }

    __shared__ float tile[64][68];      // [c][n_local], padded
    const int b  = bi / NBC;
    const int n0 = (bi % NBC) * TNC;
    const float* xbase = x + (size_t)b * C_ * N_;
    #pragma unroll
    for (int r = 0; r < 4; ++r) {
        int flat = r * 256 + t;
        int c = flat >> 4, ng = (flat & 15) * 4;
        int n = n0 + ng;
        float4 v;
        if (n + 3 < N_) {
            v = *(const float4*)&xbase[c * N_ + n];
        } else {
            v.x = (n     < N_) ? xbase[c * N_ + n    ] : 0.0f;
            v.y = (n + 1 < N_) ? xbase[c * N_ + n + 1] : 0.0f;
            v.z = (n + 2 < N_) ? xbase[c * N_ + n + 2] : 0.0f;
            v.w = (n + 3 < N_) ? xbase[c * N_ + n + 3] : 0.0f;
        }
        *(float4*)&tile[c][ng] = v;
    }
    __syncthreads();

    const int n = t >> 2, q = t & 3;    // node row, 16-channel quarter
    if (n0 + n < N_) {
        u32 p[8];
        #pragma unroll
        for (int jj = 0; jj < 8; ++jj) {
            float v0 = tile[q * 16 + 2 * jj][n];
            float v1 = tile[q * 16 + 2 * jj + 1][n];
            p[jj] = (u32)f2bf(v0) | ((u32)f2bf(v1) << 16);
        }
        u16* dst = xb + ((size_t)(b * N_ + n0 + n)) * 64 + q * 16;
        *(uint4*)dst       = make_uint4(p[0], p[1], p[2], p[3]);
        *(uint4*)(dst + 8) = make_uint4(p[4], p[5], p[6], p[7]);
    }
}

// ---------------------------------------------------------------------------
// fused: block = 16 nodes (256 edges), 4 waves; wave w owns nodes
// {w, 4+w, 8+w, 12+w}. Per node: GATHER-TO-FRAGMENT — lane l loads the
// 16 B chunks x[i1] lo/hi and x[i0] lo/hi for edge (l&15); these ARE the
// four A-fragments of mfma_16x16x32 (row = l&15, k-slice = (l>>4)*8;
// layout verified in round 4). 16 MFMAs/node vs 4 W-fragment sets:
//   ac_o = xi_lo*(W1-W2)[0:32] + xi_hi*(W1-W2)[32:64]
//        + xj_lo*W2[0:32]      + xj_hi*W2[32:64]
// Epilogue: relu(D+b)*s, k-max over D rows (reg + shfl 16/32).
// No feat LDS (72 KB -> 6 KB), no staging barrier, no bfsub VALU.
// ---------------------------------------------------------------------------
__global__ __launch_bounds__(256)
void fused(const int* __restrict__ ei, const float* __restrict__ pos,
           const u16* __restrict__ xb, const u16* __restrict__ wfrag,
           const float* __restrict__ bias, float* __restrict__ out) {
    __shared__ uint2 esl[256];          // (i0 | i1<<16, s) per edge
    __shared__ float otile[16][66];     // [n_local][o], padded

    const int bi   = blockIdx.x;
    const int b    = bi / NB;
    const int n0   = (bi % NB) * TN;
    const int t    = threadIdx.x;
    const int lane = t & 63;
    const int w    = t >> 6;
    const int g    = lane >> 4;         // k-slice group 0..3
    const int col  = lane & 15;

    // ---- Phase A: edge prep (1 edge/thread, coalesced) ----
    {
        const int idx = n0 * K_ + t;
        int i0 = ei[(size_t)b * N_ * K_ + idx];          // neighbor (x_j)
        int i1 = ei[((size_t)B_ + b) * N_ * K_ + idx];   // center   (x_i)
        const float* pb = pos + (size_t)b * 3 * N_;
        float dx = pb[i0]          - pb[i1];
        float dy = pb[N_ + i0]     - pb[N_ + i1];
        float dz = pb[2 * N_ + i0] - pb[2 * N_ + i1];
        float dis = sqrtf(dx * dx + dy * dy + dz * dz);
        float s = 2.0f / (1.0f + __expf(dis));           // 2*sigmoid(-dis)
        esl[t] = make_uint2((u32)i0 | ((u32)i1 << 16), __float_as_uint(s));
    }

    // ---- W fragments (16 x 16 B coalesced, L2-hot) + bias ----
    bf16x8 wf[16];
    #pragma unroll
    for (int f = 0; f < 16; ++f)
        wf[f] = *(const bf16x8*)&wfrag[(size_t)(f * 64 + lane) * 8];
    const float bo0 = bias[col], bo1 = bias[16 + col],
                bo2 = bias[32 + col], bo3 = bias[48 + col];
    __syncthreads();

    const uint4* xrow = (const uint4*)(xb + (size_t)b * N_ * 64);

    #pragma unroll
    for (int it = 0; it < 4; ++it) {
        const int nt = it * 4 + w;                       // this wave's node
        uint2 ee = esl[nt * 16 + col];                   // edge (l&15)
        int   i0 = (int)(ee.x & 0xFFFFu);
        int   i1 = (int)(ee.x >> 16);
        const uint4* ri = xrow + ((size_t)i1 << 3);      // 128 B row, 8 uint4
        const uint4* rj = xrow + ((size_t)i0 << 3);
        bf16x8 xi_lo = asbf(ri[g]);                      // ch g*8   .. +8
        bf16x8 xi_hi = asbf(ri[4 + g]);                  // ch 32+g*8.. +8
        bf16x8 xj_lo = asbf(rj[g]);
        bf16x8 xj_hi = asbf(rj[4 + g]);

        f32x4 ac0 = {0,0,0,0}, ac1 = ac0, ac2 = ac0, ac3 = ac0;
        ac0 = __builtin_amdgcn_mfma_f32_16x16x32_bf16(xi_lo, wf[0],  ac0, 0,0,0);
        ac0 = __builtin_amdgcn_mfma_f32_16x16x32_bf16(xi_hi, wf[1],  ac0, 0,0,0);
        ac0 = __builtin_amdgcn_mfma_f32_16x16x32_bf16(xj_lo, wf[2],  ac0, 0,0,0);
        ac0 = __builtin_amdgcn_mfma_f32_16x16x32_bf16(xj_hi, wf[3],  ac0, 0,0,0);
        ac1 = __builtin_amdgcn_mfma_f32_16x16x32_bf16(xi_lo, wf[4],  ac1, 0,0,0);
        ac1 = __builtin_amdgcn_mfma_f32_16x16x32_bf16(xi_hi, wf[5],  ac1, 0,0,0);
        ac1 = __builtin_amdgcn_mfma_f32_16x16x32_bf16(xj_lo, wf[6],  ac1, 0,0,0);
        ac1 = __builtin_amdgcn_mfma_f32_16x16x32_bf16(xj_hi, wf[7],  ac1, 0,0,0);
        ac2 = __builtin_amdgcn_mfma_f32_16x16x32_bf16(xi_lo, wf[8],  ac2, 0,0,0);
        ac2 = __builtin_amdgcn_mfma_f32_16x16x32_bf16(xi_hi, wf[9],  ac2, 0,0,0);
        ac2 = __builtin_amdgcn_mfma_f32_16x16x32_bf16(xj_lo, wf[10], ac2, 0,0,0);
        ac2 = __builtin_amdgcn_mfma_f32_16x16x32_bf16(xj_hi, wf[11], ac2, 0,0,0);
        ac3 = __builtin_amdgcn_mfma_f32_16x16x32_bf16(xi_lo, wf[12], ac3, 0,0,0);
        ac3 = __builtin_amdgcn_mfma_f32_16x16x32_bf16(xi_hi, wf[13], ac3, 0,0,0);
        ac3 = __builtin_amdgcn_mfma_f32_16x16x32_bf16(xj_lo, wf[14], ac3, 0,0,0);
        ac3 = __builtin_amdgcn_mfma_f32_16x16x32_bf16(xj_hi, wf[15], ac3, 0,0,0);

        float m0 = 0.f, m1 = 0.f, m2 = 0.f, m3 = 0.f;    // relu*s >= 0
#define EPI(REG) { \
        float sv = uasf(esl[nt * 16 + g * 4 + REG].y); \
        m0 = fmaxf(m0, fmaxf(ac0[REG] + bo0, 0.f) * sv); \
        m1 = fmaxf(m1, fmaxf(ac1[REG] + bo1, 0.f) * sv); \
        m2 = fmaxf(m2, fmaxf(ac2[REG] + bo2, 0.f) * sv); \
        m3 = fmaxf(m3, fmaxf(ac3[REG] + bo3, 0.f) * sv); }
        EPI(0) EPI(1) EPI(2) EPI(3)
#undef EPI
        m0 = fmaxf(m0, __shfl_xor(m0, 16)); m0 = fmaxf(m0, __shfl_xor(m0, 32));
        m1 = fmaxf(m1, __shfl_xor(m1, 16)); m1 = fmaxf(m1, __shfl_xor(m1, 32));
        m2 = fmaxf(m2, __shfl_xor(m2, 16)); m2 = fmaxf(m2, __shfl_xor(m2, 32));
        m3 = fmaxf(m3, __shfl_xor(m3, 16)); m3 = fmaxf(m3, __shfl_xor(m3, 32));
        if (lane < 16) {
            otile[nt][col]      = m0;
            otile[nt][16 + col] = m1;
            otile[nt][32 + col] = m2;
            otile[nt][48 + col] = m3;
        }
    }
    __syncthreads();

    // ---- coalesced writeback: 64 o x 16 n, nontemporal ----
    #pragma unroll
    for (int r = 0; r < 4; ++r) {
        int flat = r * 256 + t;
        int o = flat >> 4, n2 = flat & 15;
        __builtin_nontemporal_store(otile[n2][o],
            &out[((size_t)b * COUT_ + o) * N_ + n0 + n2]);
    }
}

// ---------------------------------------------------------------------------
extern "C" void kernel_launch(void* const* d_in, const int* in_sizes, int n_in,
                              void* d_out, int out_size, void* d_ws, size_t ws_size,
                              hipStream_t stream) {
    const float* x    = (const float*)d_in[0];   // [B, C, N, 1]
    const int*   ei   = (const int*)  d_in[1];   // [2, B, N, K]
    const float* pos  = (const float*)d_in[2];   // [B, 3, N, 1]
    const float* W    = (const float*)d_in[3];   // [COUT, 2C]
    const float* bias = (const float*)d_in[4];   // [COUT]
    float*       out  = (float*)d_out;           // [B, COUT, N, 1]

    u16* xb    = (u16*)d_ws;                     // B*N*64 bf16 = 5.12 MB
    u16* wfrag = xb + (size_t)B_ * N_ * 64;      // 16 KB (B-frag layout)

    hipLaunchKernelGGL(precast, dim3(B_ * NBC + 1), dim3(256), 0, stream,
                       x, W, xb, wfrag);
    hipLaunchKernelGGL(fused, dim3(B_ * NB), dim3(256), 0, stream,
                       ei, pos, xb, wfrag, bias, out);
}